// Round 9
// baseline (320.925 us; speedup 1.0000x reference)
//
#include <hip/hip_runtime.h>
#include <hip/hip_bf16.h>

#define S_LEN 2048
#define D_MODEL 1024
#define NH 16
#define HDIM 64
#define B_SZ 4

typedef __attribute__((ext_vector_type(8))) short bf16x8;
typedef __attribute__((ext_vector_type(4))) float f32x4;

__device__ inline void gld16(const __hip_bfloat16* g, __hip_bfloat16* l) {
    __builtin_amdgcn_global_load_lds(
        (const __attribute__((address_space(1))) unsigned int*)g,
        (__attribute__((address_space(3))) unsigned int*)l, 16, 0, 0);
}

__device__ inline unsigned int pkbf(float a, float b) {
    float2 f; f.x = a; f.y = b;
    __hip_bfloat162 h = __float22bfloat162_rn(f);
    union { __hip_bfloat162 h; unsigned int u; } cv; cv.h = h; return cv.u;
}

// ---------------- fp32 -> bf16 convert (vectorized x4) ----------------
__global__ __launch_bounds__(256) void f2bf4_kernel(const float4* __restrict__ in,
                                                    __hip_bfloat162* __restrict__ out,
                                                    int n4) {
    int i = blockIdx.x * 256 + threadIdx.x;
    if (i < n4) {
        float4 v = in[i];
        __hip_bfloat162 a, b;
        a.x = __float2bfloat16(v.x); a.y = __float2bfloat16(v.y);
        b.x = __float2bfloat16(v.z); b.y = __float2bfloat16(v.w);
        out[2 * i]     = a;
        out[2 * i + 1] = b;
    }
}

// all four weight matrices in one launch (y picks the weight)
__global__ __launch_bounds__(256) void f2bfw_kernel(
    const float4* __restrict__ w0, const float4* __restrict__ w1,
    const float4* __restrict__ w2, const float4* __restrict__ w3,
    __hip_bfloat162* __restrict__ o0, __hip_bfloat162* __restrict__ o1,
    __hip_bfloat162* __restrict__ o2, __hip_bfloat162* __restrict__ o3) {
    const int z = blockIdx.y;
    const float4* in = (z == 0) ? w0 : (z == 1) ? w1 : (z == 2) ? w2 : w3;
    __hip_bfloat162* out = (z == 0) ? o0 : (z == 1) ? o1 : (z == 2) ? o2 : o3;
    int i = blockIdx.x * 256 + threadIdx.x;   // 262144 float4 per weight
    float4 v = in[i];
    __hip_bfloat162 a, b;
    a.x = __float2bfloat16(v.x); a.y = __float2bfloat16(v.y);
    b.x = __float2bfloat16(v.z); b.y = __float2bfloat16(v.w);
    out[2 * i]     = a;
    out[2 * i + 1] = b;
}

// ---------------- 256x256 BK=64 8-wave 8-phase GEMM (counted vmcnt) ---------
// m201-template port: per K-tile 4 phases, each {frag ds_reads | stage-issue
// | s_barrier | setprio MFMA x16 | s_barrier}; ONE s_waitcnt vmcnt(6) per
// K-tile (vmcnt(0) only at the t=14 tail) so prefetched global_load_lds DMA
// stays in flight across barriers instead of draining every step.
// Wave grid 4M x 2N, interleaved 16-row stripes:
//   wr=wv>>1: A rows mt*64+wr*16+l15 (mt 0..3; LDS A-half = mt>>1)
//   wc=wv&1 : B rows nt*32+wc*16+l15 (nt 0..7; LDS B-half = nt>>2)
//   (keeps RoPE pairs hd,hd+32 within one wave: nt even/odd)
// Phase q: mh=q&1 (af re-read per phase), nh=q>>1 (bfr held across q pairs).
// Stage schedule: q0: A.h1(t+1) | q1: B.h0(t+2) | q3: A.h0(t+2)+B.h1(t+2)
//   (each target region dead >=1 barrier before the issue).
// LDS: A[2buf][256x64] + B[2buf][256x64] = 128 KB dynamic.
// XOR chunk swizzle both-sides (inverse-swizzled global src, swizzled read).
__device__ inline void gemm8p(const __hip_bfloat16* __restrict__ X,
                              const __hip_bfloat16* __restrict__ W,
                              __hip_bfloat16* Al, __hip_bfloat16* Bl,
                              int m0, int n0, f32x4 acc[4][8]) {
    const int tid = threadIdx.x;
    const int wv = tid >> 6, lane = tid & 63, l15 = lane & 15, quad = lane >> 4;
    const int wr = wv >> 1, wc = wv & 1;
    const int l7 = l15 & 7;
    const int wr16l = wr * 16 + l15;
    const int wc16l = wc * 16 + l15;
    const int sr = tid >> 3;                        // staging row 0..63
    const int sc8 = ((tid & 7) ^ (sr & 7)) * 8;     // inverse-swizzled chunk
    const __hip_bfloat16* xs = X + (size_t)(m0 + sr) * D_MODEL + sc8;
    const __hip_bfloat16* ws = W + (size_t)(n0 + sr) * D_MODEL + sc8;
    const int ldd = tid * 8;

#define SA8(bf_, h_, kt_) { \
    gld16(xs + (size_t)((h_)*128)      * D_MODEL + (kt_)*64, Al + (bf_)*16384 + ((h_)*2)*4096 + ldd); \
    gld16(xs + (size_t)((h_)*128 + 64) * D_MODEL + (kt_)*64, Al + (bf_)*16384 + ((h_)*2+1)*4096 + ldd); }
#define SB8(bf_, h_, kt_) { \
    gld16(ws + (size_t)((h_)*128)      * D_MODEL + (kt_)*64, Bl + (bf_)*16384 + ((h_)*2)*4096 + ldd); \
    gld16(ws + (size_t)((h_)*128 + 64) * D_MODEL + (kt_)*64, Bl + (bf_)*16384 + ((h_)*2+1)*4096 + ldd); }

    // prologue: tile0 complete + tile1 all-but-A.h1 (A.h1(1) issues at t0 q0)
    SB8(0, 0, 0); SA8(0, 0, 0); SB8(0, 1, 0); SA8(0, 1, 0);
    SB8(1, 0, 1); SA8(1, 0, 1); SB8(1, 1, 1);
    asm volatile("s_waitcnt vmcnt(6)" ::: "memory");   // tile0 landed; 3 units fly
    __builtin_amdgcn_s_barrier();

    for (int t = 0; t < 16; t++) {
        const int buf = t & 1;
        const __hip_bfloat16* Ab = Al + buf * 16384;
        const __hip_bfloat16* Bb = Bl + buf * 16384;
        bf16x8 af[2][2], bfr[4][2];

        // ---- q0: bfr <- B.h0, af <- A rows 0..127 ----
#pragma unroll
        for (int nl = 0; nl < 4; nl++)
#pragma unroll
            for (int kc = 0; kc < 2; kc++)
                bfr[nl][kc] = *(const bf16x8*)&Bb[(nl * 32 + wc16l) * 64 + ((kc * 4 + quad) ^ l7) * 8];
#pragma unroll
        for (int ml = 0; ml < 2; ml++)
#pragma unroll
            for (int kc = 0; kc < 2; kc++)
                af[ml][kc] = *(const bf16x8*)&Ab[(ml * 64 + wr16l) * 64 + ((kc * 4 + quad) ^ l7) * 8];
        if (t + 1 < 16) SA8(buf ^ 1, 1, t + 1);
        __builtin_amdgcn_s_barrier();
        __builtin_amdgcn_s_setprio(1);
#pragma unroll
        for (int ml = 0; ml < 2; ml++)
#pragma unroll
            for (int nl = 0; nl < 4; nl++)
#pragma unroll
                for (int kc = 0; kc < 2; kc++)
                    acc[ml][nl] = __builtin_amdgcn_mfma_f32_16x16x32_bf16(
                        af[ml][kc], bfr[nl][kc], acc[ml][nl], 0, 0, 0);
        __builtin_amdgcn_s_setprio(0);
        __builtin_amdgcn_s_barrier();

        // ---- q1: af <- A rows 128..255 (bfr held) ----
#pragma unroll
        for (int ml = 0; ml < 2; ml++)
#pragma unroll
            for (int kc = 0; kc < 2; kc++)
                af[ml][kc] = *(const bf16x8*)&Ab[(128 + ml * 64 + wr16l) * 64 + ((kc * 4 + quad) ^ l7) * 8];
        if (t + 2 < 16) SB8(buf, 0, t + 2);
        __builtin_amdgcn_s_barrier();
        __builtin_amdgcn_s_setprio(1);
#pragma unroll
        for (int ml = 0; ml < 2; ml++)
#pragma unroll
            for (int nl = 0; nl < 4; nl++)
#pragma unroll
                for (int kc = 0; kc < 2; kc++)
                    acc[2 + ml][nl] = __builtin_amdgcn_mfma_f32_16x16x32_bf16(
                        af[ml][kc], bfr[nl][kc], acc[2 + ml][nl], 0, 0, 0);
        __builtin_amdgcn_s_setprio(0);
        __builtin_amdgcn_s_barrier();

        // ---- q2: bfr <- B.h1, af <- A rows 0..127 ----
#pragma unroll
        for (int nl = 0; nl < 4; nl++)
#pragma unroll
            for (int kc = 0; kc < 2; kc++)
                bfr[nl][kc] = *(const bf16x8*)&Bb[(128 + nl * 32 + wc16l) * 64 + ((kc * 4 + quad) ^ l7) * 8];
#pragma unroll
        for (int ml = 0; ml < 2; ml++)
#pragma unroll
            for (int kc = 0; kc < 2; kc++)
                af[ml][kc] = *(const bf16x8*)&Ab[(ml * 64 + wr16l) * 64 + ((kc * 4 + quad) ^ l7) * 8];
        __builtin_amdgcn_s_barrier();
        __builtin_amdgcn_s_setprio(1);
#pragma unroll
        for (int ml = 0; ml < 2; ml++)
#pragma unroll
            for (int nl = 0; nl < 4; nl++)
#pragma unroll
                for (int kc = 0; kc < 2; kc++)
                    acc[ml][4 + nl] = __builtin_amdgcn_mfma_f32_16x16x32_bf16(
                        af[ml][kc], bfr[nl][kc], acc[ml][4 + nl], 0, 0, 0);
        __builtin_amdgcn_s_setprio(0);
        __builtin_amdgcn_s_barrier();

        // ---- q3: af <- A rows 128..255 (bfr held) ----
#pragma unroll
        for (int ml = 0; ml < 2; ml++)
#pragma unroll
            for (int kc = 0; kc < 2; kc++)
                af[ml][kc] = *(const bf16x8*)&Ab[(128 + ml * 64 + wr16l) * 64 + ((kc * 4 + quad) ^ l7) * 8];
        if (t + 2 < 16) { SA8(buf, 0, t + 2); SB8(buf, 1, t + 2); }
        __builtin_amdgcn_s_barrier();
        __builtin_amdgcn_s_setprio(1);
#pragma unroll
        for (int ml = 0; ml < 2; ml++)
#pragma unroll
            for (int nl = 0; nl < 4; nl++)
#pragma unroll
                for (int kc = 0; kc < 2; kc++)
                    acc[2 + ml][4 + nl] = __builtin_amdgcn_mfma_f32_16x16x32_bf16(
                        af[ml][kc], bfr[nl][kc], acc[2 + ml][4 + nl], 0, 0, 0);
        __builtin_amdgcn_s_setprio(0);
        if (t == 14)      asm volatile("s_waitcnt vmcnt(0)" ::: "memory");
        else if (t < 14)  asm volatile("s_waitcnt vmcnt(6)" ::: "memory");
        __builtin_amdgcn_s_barrier();
    }
#undef SA8
#undef SB8
}

// ---------------- QKV projection + RoPE + scatter ----------------------------
// 8-phase 256^2 mainloop; z=0 Q (RoPE, pre-scaled 1/8*log2e), z=1 K (RoPE),
// z=2 V -> transposed [B,H,hd,S] via 4-head LDS-bounce epilogue.
// acc col n = n0 + nt*32 + wc*16 + l15: head j = nt>>1, hd = (nt&1)*32+wc*16+l15
// -> RoPE pair (hd, hd+32) = (nt=2j, nt=2j+1), in-wave, in-register.
#define PT8 264  // V-transpose pitch: 528B rows, 16B-aligned
__global__ __launch_bounds__(512, 2) void qkv_kernel(
    const __hip_bfloat16* __restrict__ X,
    const __hip_bfloat16* __restrict__ W0, const __hip_bfloat16* __restrict__ W1,
    const __hip_bfloat16* __restrict__ W2,
    const float* __restrict__ b0, const float* __restrict__ b1,
    const float* __restrict__ b2,
    const float* __restrict__ rc, const float* __restrict__ rs,
    __hip_bfloat16* __restrict__ Qo, __hip_bfloat16* __restrict__ Ko,
    __hip_bfloat16* __restrict__ Vo) {
    extern __shared__ __hip_bfloat16 lds[];        // 131072 B dynamic
    __hip_bfloat16* Al = lds;                      // [2][16384]
    __hip_bfloat16* Bl = lds + 32768;              // [2][16384]
    const int z = blockIdx.z;
    const __hip_bfloat16* W = (z == 0) ? W0 : ((z == 1) ? W1 : W2);
    const float* bias = (z == 0) ? b0 : ((z == 1) ? b1 : b2);
    f32x4 acc[4][8];
#pragma unroll
    for (int i = 0; i < 4; i++)
#pragma unroll
        for (int j = 0; j < 8; j++) acc[i][j] = (f32x4){0.f, 0.f, 0.f, 0.f};
    const int m0 = blockIdx.x * 256, n0 = blockIdx.y * 256;
    gemm8p(X, W, Al, Bl, m0, n0, acc);

    const int tid = threadIdx.x;
    const int wv = tid >> 6, lane = tid & 63, l15 = lane & 15, quad = lane >> 4;
    const int wr = wv >> 1, wc = wv & 1;

    if (z == 2) {
        // transpose epilogue: per head j, acc -> T[d][s] -> VT[b][h][d][s]
        __hip_bfloat16* T = Al;   // 64 x PT8 = 16896 elems
        const int b = m0 >> 11, s0l = m0 & (S_LEN - 1);
#pragma unroll
        for (int j = 0; j < 4; j++) {
            __syncthreads();   // LDS free (mainloop done / prev head read)
#pragma unroll
            for (int mt = 0; mt < 4; mt++)
#pragma unroll
                for (int e = 0; e < 2; e++) {
                    int hd = e * 32 + wc * 16 + l15;
#pragma unroll
                    for (int r = 0; r < 4; r++) {
                        int mloc = mt * 64 + wr * 16 + quad * 4 + r;
                        T[hd * PT8 + mloc] =
                            __float2bfloat16(acc[mt][2 * j + e][r] + bias[n0 + j * 64 + hd]);
                    }
                }
            __syncthreads();
            const int d = tid >> 3, sc = tid & 7;
            const int h = (n0 >> 6) + j;
            size_t gb = ((size_t)((b * NH + h) * HDIM + d)) * S_LEN + s0l + sc * 32;
#pragma unroll
            for (int j8 = 0; j8 < 4; j8++) {
                bf16x8 v = *(const bf16x8*)&T[d * PT8 + sc * 32 + j8 * 8];
                *(bf16x8*)&Vo[gb + j8 * 8] = v;
            }
        }
        return;
    }

    // Q/K epilogue: in-register RoPE
    __hip_bfloat16* dst = (z == 0) ? Qo : Ko;
    const float qs = (z == 0) ? 0.18033688011112042f : 1.0f;  // 1/8*log2(e)
    const int hd1 = wc * 16 + l15;   // 0..31
#pragma unroll
    for (int mt = 0; mt < 4; mt++)
#pragma unroll
        for (int r = 0; r < 4; r++) {
            int m = m0 + mt * 64 + wr * 16 + quad * 4 + r;
            int s = m & (S_LEN - 1), b = m >> 11;
            float c1 = rc[s * HDIM + hd1], s1 = rs[s * HDIM + hd1];
            float c2 = rc[s * HDIM + hd1 + 32], s2 = rs[s * HDIM + hd1 + 32];
#pragma unroll
            for (int j = 0; j < 4; j++) {
                int h = (n0 >> 6) + j;
                float y1 = acc[mt][2 * j][r] + bias[n0 + j * 64 + hd1];
                float y2 = acc[mt][2 * j + 1][r] + bias[n0 + j * 64 + hd1 + 32];
                size_t base = (((size_t)(b * NH + h)) * S_LEN + s) * HDIM;
                dst[base + hd1]      = __float2bfloat16((y1 * c1 - y2 * s1) * qs);
                dst[base + hd1 + 32] = __float2bfloat16((y2 * c2 + y1 * s2) * qs);
            }
        }
}

// ---------------- flash attention, balanced causal pairing ------------------
// unchanged (101.5us): global_load_lds staging w/ pre-swizzled source, V^T
// input, double-buffered K/V, one barrier/iter, no setprio.
#define SWZ(r, c) (((r) << 6) + ((c) ^ (((r) & 7) << 3)))
__global__ __launch_bounds__(256) void attn_kernel(
    const __hip_bfloat16* __restrict__ Q, const __hip_bfloat16* __restrict__ K,
    const __hip_bfloat16* __restrict__ VT, __hip_bfloat16* __restrict__ CTX) {
    __shared__ __hip_bfloat16 Kl[2][64 * 64];      // 16 KB
    __shared__ __hip_bfloat16 Vl[2][64 * 64];      // 16 KB (V^T[d][k], swizzled)
    __shared__ __hip_bfloat16 Pl[2][4][16 * 64];   // 16 KB [tile][wave][q][k]
    const int tid = threadIdx.x;
    const int wv = tid >> 6, lane = tid & 63, l15 = lane & 15, quad = lane >> 4;
    const int bh = blockIdx.x;          // same-head blocks share an XCD (%8)
    const int pr = blockIdx.y;          // pair index 0..15
    const int tA = pr, tC = 31 - pr;
    const int nkb = tC + 1;
    const size_t off = (size_t)bh * S_LEN * HDIM;
    const __hip_bfloat16* Qp = Q + off;
    const __hip_bfloat16* Kp = K + off;
    const __hip_bfloat16* Vp = VT + off;   // [d][s]
    __hip_bfloat16* PC = &Pl[0][wv][0];
    __hip_bfloat16* PA = &Pl[1][wv][0];

    // per-lane pre-swizzled global sources for the two gld16 calls per buffer
    const int e0 = wv * 512 + lane * 8;          // LDS elem of call 0
    const int r0 = e0 >> 6, c80 = e0 & 63;       // tile row / 8-col chunk
    const int sw0 = c80 ^ ((r0 & 7) << 3);
    const int r1 = r0 + 32;                      // call 1 = +2048 elems
    const int sw1 = c80 ^ ((r1 & 7) << 3);
    const __hip_bfloat16* ks0 = Kp + r0 * 64 + sw0;          // + kb*4096
    const __hip_bfloat16* ks1 = Kp + r1 * 64 + sw1;
    const __hip_bfloat16* vs0 = Vp + (size_t)r0 * S_LEN + sw0;  // + kb*64
    const __hip_bfloat16* vs1 = Vp + (size_t)r1 * S_LEN + sw1;

    auto stage = [&](int kb, int bsel) {
        const int ko = kb * 64;
        gld16(ks0 + (size_t)ko * 64, &Kl[bsel][e0]);
        gld16(ks1 + (size_t)ko * 64, &Kl[bsel][e0 + 2048]);
        gld16(vs0 + ko, &Vl[bsel][e0]);
        gld16(vs1 + ko, &Vl[bsel][e0 + 2048]);
    };

    // Q fragments (B-operand of S^T MFMA)
    bf16x8 qfA[2], qfC[2];
#pragma unroll
    for (int c = 0; c < 2; c++) {
        qfA[c] = *(const bf16x8*)&Qp[(size_t)(tA * 64 + wv * 16 + l15) * HDIM + c * 32 + quad * 8];
        qfC[c] = *(const bf16x8*)&Qp[(size_t)(tC * 64 + wv * 16 + l15) * HDIM + c * 32 + quad * 8];
    }

    float lA = 0.f, lC = 0.f;
    f32x4 accA[4], accC[4];
#pragma unroll
    for (int nt = 0; nt < 4; nt++) {
        accA[nt] = (f32x4){0.f, 0.f, 0.f, 0.f};
        accC[nt] = (f32x4){0.f, 0.f, 0.f, 0.f};
    }

    const int qrel = wv * 16 + l15;

    stage(0, 0);
    __syncthreads();   // drains vmcnt(0) + barrier: buf0 ready
    for (int kb = 0; kb < nkb; kb++) {
        const int buf = kb & 1;
        if (kb + 1 < nkb) stage(kb + 1, buf ^ 1);   // drains under compute
        const __hip_bfloat16* Kb_ = &Kl[buf][0];
        const __hip_bfloat16* Vb_ = &Vl[buf][0];

        const bool aAct = (kb <= tA);
        unsigned int pkC[8], pkA[8];

        // ---- scores, both tiles from one Kl fragment load ----
        f32x4 saC[4], saA[4];
#pragma unroll
        for (int st = 0; st < 4; st++) {
            saC[st] = (f32x4){0.f, 0.f, 0.f, 0.f};
            saA[st] = (f32x4){0.f, 0.f, 0.f, 0.f};
        }
        if (aAct) {
#pragma unroll
            for (int c = 0; c < 2; c++)
#pragma unroll
                for (int st = 0; st < 4; st++) {
                    bf16x8 kf = *(const bf16x8*)&Kb_[SWZ(st * 16 + l15, c * 32 + quad * 8)];
                    saC[st] = __builtin_amdgcn_mfma_f32_16x16x32_bf16(kf, qfC[c], saC[st], 0, 0, 0);
                    saA[st] = __builtin_amdgcn_mfma_f32_16x16x32_bf16(kf, qfA[c], saA[st], 0, 0, 0);
                }
        } else {
#pragma unroll
            for (int c = 0; c < 2; c++)
#pragma unroll
                for (int st = 0; st < 4; st++) {
                    bf16x8 kf = *(const bf16x8*)&Kb_[SWZ(st * 16 + l15, c * 32 + quad * 8)];
                    saC[st] = __builtin_amdgcn_mfma_f32_16x16x32_bf16(kf, qfC[c], saC[st], 0, 0, 0);
                }
        }

        // ---- tile C softmax + P write ----
        {
            float ls = 0.f;
            if (kb == tC) {  // wave-uniform: only diagonal update pays mask cost
#pragma unroll
                for (int st = 0; st < 4; st++) {
                    float p[4];
#pragma unroll
                    for (int r = 0; r < 4; r++) {
                        bool msk = (st * 16 + quad * 4 + r > qrel);
                        p[r] = msk ? 0.f : __builtin_exp2f(saC[st][r]);
                        ls += p[r];
                    }
                    pkC[st * 2 + 0] = pkbf(p[0], p[1]);
                    pkC[st * 2 + 1] = pkbf(p[2], p[3]);
                }
            } else {
#pragma unroll
                for (int st = 0; st < 4; st++) {
                    float p[4];
#pragma unroll
                    for (int r = 0; r < 4; r++) {
                        p[r] = __builtin_exp2f(saC[st][r]);
                        ls += p[r];
                    }
                    pkC[st * 2 + 0] = pkbf(p[0], p[1]);
                    pkC[st * 2 + 1] = pkbf(p[2], p[3]);
                }
            }
            ls += __shfl_xor(ls, 16);
            ls += __shfl_xor(ls, 32);
            lC += ls;
#pragma unroll
            for (int st = 0; st < 4; st++) {
                uint2 w; w.x = pkC[st * 2]; w.y = pkC[st * 2 + 1];
                *(uint2*)&PC[SWZ(l15, st * 16 + quad * 4)] = w;
            }
        }
        // ---- tile A softmax + P write ----
        if (aAct) {
            float ls = 0.f;
            if (kb == tA) {
#pragma unroll
                for (int st = 0; st < 4; st++) {
                    float p[4];
#pragma unroll
                    for (int r = 0; r < 4; r++) {
                        bool msk = (st * 16 + quad * 4 + r > qrel);
                        p[r] = msk ? 0.f : __builtin_exp2f(saA[st][r]);
                        ls += p[r];
                    }
                    pkA[st * 2 + 0] = pkbf(p[0], p[1]);
                    pkA[st * 2 + 1] = pkbf(p[2], p[3]);
                }
            } else {
#pragma unroll
                for (int st = 0; st < 4; st++) {
                    float p[4];
#pragma unroll
                    for (int r = 0; r < 4; r++) {
                        p[r] = __builtin_exp2f(saA[st][r]);
                        ls += p[r];
                    }
                    pkA[st * 2 + 0] = pkbf(p[0], p[1]);
                    pkA[st * 2 + 1] = pkbf(p[2], p[3]);
                }
            }
            ls += __shfl_xor(ls, 16);
            ls += __shfl_xor(ls, 32);
            lA += ls;
#pragma unroll
            for (int st = 0; st < 4; st++) {
                uint2 w; w.x = pkA[st * 2]; w.y = pkA[st * 2 + 1];
                *(uint2*)&PA[SWZ(l15, st * 16 + quad * 4)] = w;
            }
        }

        // ---- PV: ctx^T += V^T · P^T (B-frags from per-wave LDS) ----
#pragma unroll
        for (int c = 0; c < 2; c++) {
            bf16x8 vf[4];
#pragma unroll
            for (int nt = 0; nt < 4; nt++)
                vf[nt] = *(const bf16x8*)&Vb_[SWZ(nt * 16 + l15, c * 32 + quad * 8)];
            {
                bf16x8 pf = *(const bf16x8*)&PC[SWZ(l15, c * 32 + quad * 8)];
#pragma unroll
                for (int nt = 0; nt < 4; nt++)
                    accC[nt] = __builtin_amdgcn_mfma_f32_16x16x32_bf16(vf[nt], pf, accC[nt], 0, 0, 0);
            }
            if (aAct) {
                bf16x8 pf = *(const bf16x8*)&PA[SWZ(l15, c * 32 + quad * 8)];
#pragma unroll
                for (int nt = 0; nt < 4; nt++)
                    accA[nt] = __builtin_amdgcn_mfma_f32_16x16x32_bf16(vf[nt], pf, accA[nt], 0, 0, 0);
            }
        }

        __syncthreads();   // drains prefetch vmcnt(0); buf^1 ready, buf free
    }

    const int b = bh >> 4, h = bh & 15;
    {
        const int q = tA * 64 + wv * 16 + l15;
        const float inv = 1.0f / lA;
#pragma unroll
        for (int nt = 0; nt < 4; nt++) {
            uint2 st2;
            st2.x = pkbf(accA[nt][0] * inv, accA[nt][1] * inv);
            st2.y = pkbf(accA[nt][2] * inv, accA[nt][3] * inv);
            *(uint2*)&CTX[((size_t)(b * S_LEN + q)) * D_MODEL + h * HDIM + nt * 16 + quad * 4] = st2;
        }
    }
    {
        const int q = tC * 64 + wv * 16 + l15;
        const float inv = 1.0f / lC;
#pragma unroll
        for (int nt = 0; nt < 4; nt++) {
            uint2 st2;
            st2.x = pkbf(accC[nt][0] * inv, accC[nt][1] * inv);
            st2.y = pkbf(accC[nt][2] * inv, accC[nt][3] * inv);
            *(uint2*)&CTX[((size_t)(b * S_LEN + q)) * D_MODEL + h * HDIM + nt * 16 + quad * 4] = st2;
        }
    }
}

// ---------------- output projection: fp32 out = ctx @ Wo^T + bo --------------
__global__ __launch_bounds__(512, 2) void outproj_kernel(
    const __hip_bfloat16* __restrict__ X, const __hip_bfloat16* __restrict__ W,
    const float* __restrict__ bias, float* __restrict__ OUT) {
    extern __shared__ __hip_bfloat16 lds[];        // 131072 B dynamic
    __hip_bfloat16* Al = lds;
    __hip_bfloat16* Bl = lds + 32768;
    f32x4 acc[4][8];
#pragma unroll
    for (int i = 0; i < 4; i++)
#pragma unroll
        for (int j = 0; j < 8; j++) acc[i][j] = (f32x4){0.f, 0.f, 0.f, 0.f};
    const int m0 = blockIdx.x * 256, n0 = blockIdx.y * 256;
    gemm8p(X, W, Al, Bl, m0, n0, acc);
    const int tid = threadIdx.x;
    const int wv = tid >> 6, lane = tid & 63, l15 = lane & 15, quad = lane >> 4;
    const int wr = wv >> 1, wc = wv & 1;
#pragma unroll
    for (int mt = 0; mt < 4; mt++)
#pragma unroll
        for (int r = 0; r < 4; r++) {
            int m = m0 + mt * 64 + wr * 16 + quad * 4 + r;
#pragma unroll
            for (int nt = 0; nt < 8; nt++) {
                int n = n0 + nt * 32 + wc * 16 + l15;
                OUT[(size_t)m * D_MODEL + n] = acc[mt][nt][r] + bias[n];
            }
        }
}

extern "C" void kernel_launch(void* const* d_in, const int* in_sizes, int n_in,
                              void* d_out, int out_size, void* d_ws, size_t ws_size,
                              hipStream_t stream) {
    const float* x  = (const float*)d_in[0];
    const float* rc = (const float*)d_in[2];
    const float* rs = (const float*)d_in[3];
    const float* Wq = (const float*)d_in[4];
    const float* bq = (const float*)d_in[5];
    const float* Wk = (const float*)d_in[6];
    const float* bk = (const float*)d_in[7];
    const float* Wv = (const float*)d_in[8];
    const float* bv = (const float*)d_in[9];
    const float* Wo = (const float*)d_in[10];
    const float* bo = (const float*)d_in[11];

    char* ws = (char*)d_ws;
    __hip_bfloat16* xbf = (__hip_bfloat16*)(ws);                    // 16 MB
    __hip_bfloat16* wqb = (__hip_bfloat16*)(ws + (16u << 20));      // 2 MB
    __hip_bfloat16* wkb = (__hip_bfloat16*)(ws + (18u << 20));
    __hip_bfloat16* wvb = (__hip_bfloat16*)(ws + (20u << 20));
    __hip_bfloat16* wob = (__hip_bfloat16*)(ws + (22u << 20));
    __hip_bfloat16* Qb  = (__hip_bfloat16*)(ws + (24u << 20));      // 16 MB
    __hip_bfloat16* Kb  = (__hip_bfloat16*)(ws + (40u << 20));
    __hip_bfloat16* Vb  = (__hip_bfloat16*)(ws + (56u << 20));      // V^T layout
    __hip_bfloat16* Cb  = (__hip_bfloat16*)(ws + (72u << 20));      // 16 MB
    float* out = (float*)d_out;

    (void)hipFuncSetAttribute((const void*)qkv_kernel,
                              hipFuncAttributeMaxDynamicSharedMemorySize, 131072);
    (void)hipFuncSetAttribute((const void*)outproj_kernel,
                              hipFuncAttributeMaxDynamicSharedMemorySize, 131072);

    f2bf4_kernel<<<8192, 256, 0, stream>>>((const float4*)x, (__hip_bfloat162*)xbf, 2097152);
    f2bfw_kernel<<<dim3(1024, 4), 256, 0, stream>>>(
        (const float4*)Wq, (const float4*)Wk, (const float4*)Wv, (const float4*)Wo,
        (__hip_bfloat162*)wqb, (__hip_bfloat162*)wkb, (__hip_bfloat162*)wvb,
        (__hip_bfloat162*)wob);

    qkv_kernel<<<dim3(32, 4, 3), 512, 131072, stream>>>(xbf, wqb, wkb, wvb, bq, bk, bv,
                                                        rc, rs, Qb, Kb, Vb);
    attn_kernel<<<dim3(64, 16), 256, 0, stream>>>(Qb, Kb, Vb, Cb);
    outproj_kernel<<<dim3(32, 4), 512, 131072, stream>>>(Cb, wob, bo, out);
}

// Round 10
// 290.108 us; speedup vs baseline: 1.1062x; 1.1062x over previous
//
#include <hip/hip_runtime.h>
#include <hip/hip_bf16.h>

#define S_LEN 2048
#define D_MODEL 1024
#define NH 16
#define HDIM 64
#define B_SZ 4

typedef __attribute__((ext_vector_type(8))) short bf16x8;
typedef __attribute__((ext_vector_type(4))) float f32x4;

__device__ inline void gld16(const __hip_bfloat16* g, __hip_bfloat16* l) {
    __builtin_amdgcn_global_load_lds(
        (const __attribute__((address_space(1))) unsigned int*)g,
        (__attribute__((address_space(3))) unsigned int*)l, 16, 0, 0);
}

__device__ inline unsigned int pkbf(float a, float b) {
    float2 f; f.x = a; f.y = b;
    __hip_bfloat162 h = __float22bfloat162_rn(f);
    union { __hip_bfloat162 h; unsigned int u; } cv; cv.h = h; return cv.u;
}

// ---------------- fp32 -> bf16 convert (vectorized x4) ----------------
__global__ __launch_bounds__(256) void f2bf4_kernel(const float4* __restrict__ in,
                                                    __hip_bfloat162* __restrict__ out,
                                                    int n4) {
    int i = blockIdx.x * 256 + threadIdx.x;
    if (i < n4) {
        float4 v = in[i];
        __hip_bfloat162 a, b;
        a.x = __float2bfloat16(v.x); a.y = __float2bfloat16(v.y);
        b.x = __float2bfloat16(v.z); b.y = __float2bfloat16(v.w);
        out[2 * i]     = a;
        out[2 * i + 1] = b;
    }
}

// all four weight matrices in one launch (y picks the weight)
__global__ __launch_bounds__(256) void f2bfw_kernel(
    const float4* __restrict__ w0, const float4* __restrict__ w1,
    const float4* __restrict__ w2, const float4* __restrict__ w3,
    __hip_bfloat162* __restrict__ o0, __hip_bfloat162* __restrict__ o1,
    __hip_bfloat162* __restrict__ o2, __hip_bfloat162* __restrict__ o3) {
    const int z = blockIdx.y;
    const float4* in = (z == 0) ? w0 : (z == 1) ? w1 : (z == 2) ? w2 : w3;
    __hip_bfloat162* out = (z == 0) ? o0 : (z == 1) ? o1 : (z == 2) ? o2 : o3;
    int i = blockIdx.x * 256 + threadIdx.x;   // 262144 float4 per weight
    float4 v = in[i];
    __hip_bfloat162 a, b;
    a.x = __float2bfloat16(v.x); a.y = __float2bfloat16(v.y);
    b.x = __float2bfloat16(v.z); b.y = __float2bfloat16(v.w);
    out[2 * i]     = a;
    out[2 * i + 1] = b;
}

// ---------------- shared GEMM mainloop: C[128x128] = X[128xK] * W[128xK]^T ----
// R8 version (302.4us best): BK=64, XOR chunk swizzle both-sides, 2-phase
// prefetch loop, 256 thr, 64 KB LDS = 2 blocks/CU.
__device__ inline void gemm_mainloop(const __hip_bfloat16* __restrict__ X,
                                     const __hip_bfloat16* __restrict__ W,
                                     __hip_bfloat16* As, __hip_bfloat16* Bs,
                                     int m0, int n0, f32x4 acc[4][4]) {
    const int tid = threadIdx.x;
    const int wv = tid >> 6, lane = tid & 63, l15 = lane & 15, quad = lane >> 4;
    const int rw = (wv >> 1) * 64, cw = (wv & 1) * 64;
    const int row_s = tid >> 3;                       // staging row 0..31 (+32*i)
    const int csw = ((tid & 7) ^ (row_s & 7)) * 8;    // inverse-swizzled chunk
    const __hip_bfloat16* xsrc = X + (size_t)(m0 + row_s) * D_MODEL + csw;
    const __hip_bfloat16* wsrc = W + (size_t)(n0 + row_s) * D_MODEL + csw;
    const int ld = tid * 8;                           // linear dest (16B/thread)

    auto stage = [&](int k0, int bsel) {
#pragma unroll
        for (int i = 0; i < 4; i++) {
            gld16(xsrc + (size_t)(i * 32) * D_MODEL + k0,
                  &As[bsel * 8192 + i * 2048 + ld]);
            gld16(wsrc + (size_t)(i * 32) * D_MODEL + k0,
                  &Bs[bsel * 8192 + i * 2048 + ld]);
        }
    };

    stage(0, 0);
    __syncthreads();   // buf0 staged
    for (int kt = 0; kt < 16; kt++) {
        const int buf = kt & 1;
        if (kt + 1 < 16) stage((kt + 1) * 64, buf ^ 1);   // drains under compute
        const __hip_bfloat16* Ab = &As[buf * 8192];
        const __hip_bfloat16* Bb = &Bs[buf * 8192];
#pragma unroll
        for (int kc = 0; kc < 2; kc++) {
            bf16x8 af[4], bfr[4];
#pragma unroll
            for (int t = 0; t < 4; t++)
                af[t] = *(const bf16x8*)&Ab[(rw + t * 16 + l15) * 64 +
                                            (((kc * 4 + quad) ^ (l15 & 7)) * 8)];
#pragma unroll
            for (int t = 0; t < 4; t++)
                bfr[t] = *(const bf16x8*)&Bb[(cw + t * 16 + l15) * 64 +
                                             (((kc * 4 + quad) ^ (l15 & 7)) * 8)];
#pragma unroll
            for (int mt = 0; mt < 4; mt++)
#pragma unroll
                for (int nt = 0; nt < 4; nt++)
                    acc[mt][nt] = __builtin_amdgcn_mfma_f32_16x16x32_bf16(
                        af[mt], bfr[nt], acc[mt][nt], 0, 0, 0);
        }
        __syncthreads();   // prefetch drained; other buf free for next stage
    }
}

// ---------------- QKV projection + RoPE + scatter ----------------------------
// R8 version: 3 z-slices, in-register RoPE, V -> [B,H,hd,S] LDS transpose.
#define PT 136  // T pitch: 272B rows, 16B-aligned
__global__ __launch_bounds__(256, 2) void qkv_kernel(
    const __hip_bfloat16* __restrict__ X,
    const __hip_bfloat16* __restrict__ W0, const __hip_bfloat16* __restrict__ W1,
    const __hip_bfloat16* __restrict__ W2,
    const float* __restrict__ b0, const float* __restrict__ b1,
    const float* __restrict__ b2,
    const float* __restrict__ rc, const float* __restrict__ rs,
    __hip_bfloat16* __restrict__ Qo, __hip_bfloat16* __restrict__ Ko,
    __hip_bfloat16* __restrict__ Vo) {
    __shared__ __hip_bfloat16 pool[32768];   // As[2][8192] + Bs[2][8192] = 64 KB
    __hip_bfloat16* As = pool;
    __hip_bfloat16* Bs = pool + 16384;
    const int z = blockIdx.z;
    const __hip_bfloat16* W = (z == 0) ? W0 : ((z == 1) ? W1 : W2);
    const float* bias = (z == 0) ? b0 : ((z == 1) ? b1 : b2);
    f32x4 acc[4][4];
#pragma unroll
    for (int i = 0; i < 4; i++)
#pragma unroll
        for (int j = 0; j < 4; j++) acc[i][j] = (f32x4){0.f, 0.f, 0.f, 0.f};
    const int m0 = blockIdx.x * 128, n0 = blockIdx.y * 128;
    gemm_mainloop(X, W, As, Bs, m0, n0, acc);

    const int tid = threadIdx.x;
    const int wv = tid >> 6, lane = tid & 63, l15 = lane & 15, quad = lane >> 4;
    const int rw = (wv >> 1) * 64, cw = (wv & 1) * 64;

    if (z == 2) {
        // transpose epilogue: acc tile [m=128][n=128] -> VT[b][h][d][s]
        __hip_bfloat16* T = pool;   // 64 x PT = 8704 elems
        const int b = m0 >> 11, s0l = m0 & (S_LEN - 1);
#pragma unroll
        for (int hn = 0; hn < 2; hn++) {
            __syncthreads();   // pool free (mainloop done / prev half read)
            if ((wv & 1) == hn) {
#pragma unroll
                for (int mt = 0; mt < 4; mt++)
#pragma unroll
                    for (int nt = 0; nt < 4; nt++)
#pragma unroll
                        for (int r = 0; r < 4; r++) {
                            int dl = nt * 16 + l15;
                            int ml = rw + mt * 16 + quad * 4 + r;
                            T[dl * PT + ml] =
                                __float2bfloat16(acc[mt][nt][r] + bias[n0 + hn * 64 + dl]);
                        }
            }
            __syncthreads();
            const int d = tid >> 2, sc = tid & 3;
            const int h = (n0 >> 6) + hn;
            size_t gb = ((size_t)((b * NH + h) * HDIM + d)) * S_LEN + s0l + sc * 32;
#pragma unroll
            for (int j = 0; j < 4; j++) {
                bf16x8 v = *(const bf16x8*)&T[d * PT + sc * 32 + j * 8];
                *(bf16x8*)&Vo[gb + j * 8] = v;
            }
        }
    } else {
        __hip_bfloat16* dst = (z == 0) ? Qo : Ko;
        const float qs = (z == 0) ? 0.18033688011112042f : 1.0f;  // 1/8*log2(e)
#pragma unroll
        for (int mt = 0; mt < 4; mt++)
#pragma unroll
            for (int r = 0; r < 4; r++) {
                int m = m0 + rw + mt * 16 + quad * 4 + r;
                int s = m & (S_LEN - 1), b = m >> 11;
#pragma unroll
                for (int nt = 0; nt < 2; nt++) {
                    int n1 = n0 + cw + nt * 16 + l15;
                    int h = n1 >> 6, hd1 = n1 & 63;  // hd1 in [0,32)
                    float y1 = acc[mt][nt][r] + bias[n1];
                    float y2 = acc[mt][nt + 2][r] + bias[n1 + 32];
                    float c1 = rc[s * HDIM + hd1], s1 = rs[s * HDIM + hd1];
                    float c2 = rc[s * HDIM + hd1 + 32], s2 = rs[s * HDIM + hd1 + 32];
                    size_t base = (((size_t)(b * NH + h)) * S_LEN + s) * HDIM;
                    dst[base + hd1]      = __float2bfloat16((y1 * c1 - y2 * s1) * qs);
                    dst[base + hd1 + 32] = __float2bfloat16((y2 * c2 + y1 * s2) * qs);
                }
            }
    }
}

// ---------------- flash attention, balanced causal pairing ------------------
// v10: occupancy fix. P staging collapsed to ONE 8 KB per-wave buffer by
// sequentializing {softmax-C -> PV-C -> softmax-A -> PV-A} (in-wave LDS
// ordering makes the buffer reuse safe; vf re-read per tile = +15% avg LDS
// traffic). LDS 48 KB -> 40 KB = 4 blocks/CU (was 3): +33% resident waves
// to overlap the LDS/VALU/MFMA streams (no pipe was saturated; occupancy
// was the binding constraint).
#define SWZ(r, c) (((r) << 6) + ((c) ^ (((r) & 7) << 3)))
__global__ __launch_bounds__(256) void attn_kernel(
    const __hip_bfloat16* __restrict__ Q, const __hip_bfloat16* __restrict__ K,
    const __hip_bfloat16* __restrict__ VT, __hip_bfloat16* __restrict__ CTX) {
    __shared__ __hip_bfloat16 Kl[2][64 * 64];      // 16 KB
    __shared__ __hip_bfloat16 Vl[2][64 * 64];      // 16 KB (V^T[d][k], swizzled)
    __shared__ __hip_bfloat16 Pl[4][16 * 64];      // 8 KB [wave][q][k] (shared C/A)
    const int tid = threadIdx.x;
    const int wv = tid >> 6, lane = tid & 63, l15 = lane & 15, quad = lane >> 4;
    const int bh = blockIdx.x;          // same-head blocks share an XCD (%8)
    const int pr = blockIdx.y;          // pair index 0..15
    const int tA = pr, tC = 31 - pr;
    const int nkb = tC + 1;
    const size_t off = (size_t)bh * S_LEN * HDIM;
    const __hip_bfloat16* Qp = Q + off;
    const __hip_bfloat16* Kp = K + off;
    const __hip_bfloat16* Vp = VT + off;   // [d][s]
    __hip_bfloat16* Pw = &Pl[wv][0];

    // per-lane pre-swizzled global sources for the two gld16 calls per buffer
    const int e0 = wv * 512 + lane * 8;          // LDS elem of call 0
    const int r0 = e0 >> 6, c80 = e0 & 63;       // tile row / 8-col chunk
    const int sw0 = c80 ^ ((r0 & 7) << 3);
    const int r1 = r0 + 32;                      // call 1 = +2048 elems
    const int sw1 = c80 ^ ((r1 & 7) << 3);
    const __hip_bfloat16* ks0 = Kp + r0 * 64 + sw0;          // + kb*4096
    const __hip_bfloat16* ks1 = Kp + r1 * 64 + sw1;
    const __hip_bfloat16* vs0 = Vp + (size_t)r0 * S_LEN + sw0;  // + kb*64
    const __hip_bfloat16* vs1 = Vp + (size_t)r1 * S_LEN + sw1;

    auto stage = [&](int kb, int bsel) {
        const int ko = kb * 64;
        gld16(ks0 + (size_t)ko * 64, &Kl[bsel][e0]);
        gld16(ks1 + (size_t)ko * 64, &Kl[bsel][e0 + 2048]);
        gld16(vs0 + ko, &Vl[bsel][e0]);
        gld16(vs1 + ko, &Vl[bsel][e0 + 2048]);
    };

    // Q fragments (B-operand of S^T MFMA)
    bf16x8 qfA[2], qfC[2];
#pragma unroll
    for (int c = 0; c < 2; c++) {
        qfA[c] = *(const bf16x8*)&Qp[(size_t)(tA * 64 + wv * 16 + l15) * HDIM + c * 32 + quad * 8];
        qfC[c] = *(const bf16x8*)&Qp[(size_t)(tC * 64 + wv * 16 + l15) * HDIM + c * 32 + quad * 8];
    }

    float lA = 0.f, lC = 0.f;
    f32x4 accA[4], accC[4];
#pragma unroll
    for (int nt = 0; nt < 4; nt++) {
        accA[nt] = (f32x4){0.f, 0.f, 0.f, 0.f};
        accC[nt] = (f32x4){0.f, 0.f, 0.f, 0.f};
    }

    const int qrel = wv * 16 + l15;

    stage(0, 0);
    __syncthreads();   // drains vmcnt(0) + barrier: buf0 ready
    for (int kb = 0; kb < nkb; kb++) {
        const int buf = kb & 1;
        if (kb + 1 < nkb) stage(kb + 1, buf ^ 1);   // drains under compute
        const __hip_bfloat16* Kb_ = &Kl[buf][0];
        const __hip_bfloat16* Vb_ = &Vl[buf][0];

        const bool aAct = (kb <= tA);
        unsigned int pk[8];

        // ---- scores, both tiles from one Kl fragment load ----
        f32x4 saC[4], saA[4];
#pragma unroll
        for (int st = 0; st < 4; st++) {
            saC[st] = (f32x4){0.f, 0.f, 0.f, 0.f};
            saA[st] = (f32x4){0.f, 0.f, 0.f, 0.f};
        }
        if (aAct) {
#pragma unroll
            for (int c = 0; c < 2; c++)
#pragma unroll
                for (int st = 0; st < 4; st++) {
                    bf16x8 kf = *(const bf16x8*)&Kb_[SWZ(st * 16 + l15, c * 32 + quad * 8)];
                    saC[st] = __builtin_amdgcn_mfma_f32_16x16x32_bf16(kf, qfC[c], saC[st], 0, 0, 0);
                    saA[st] = __builtin_amdgcn_mfma_f32_16x16x32_bf16(kf, qfA[c], saA[st], 0, 0, 0);
                }
        } else {
#pragma unroll
            for (int c = 0; c < 2; c++)
#pragma unroll
                for (int st = 0; st < 4; st++) {
                    bf16x8 kf = *(const bf16x8*)&Kb_[SWZ(st * 16 + l15, c * 32 + quad * 8)];
                    saC[st] = __builtin_amdgcn_mfma_f32_16x16x32_bf16(kf, qfC[c], saC[st], 0, 0, 0);
                }
        }

        // ---- tile C: softmax -> P -> PV ----
        {
            float ls = 0.f;
            if (kb == tC) {  // wave-uniform: only diagonal update pays mask cost
#pragma unroll
                for (int st = 0; st < 4; st++) {
                    float p[4];
#pragma unroll
                    for (int r = 0; r < 4; r++) {
                        bool msk = (st * 16 + quad * 4 + r > qrel);
                        p[r] = msk ? 0.f : __builtin_exp2f(saC[st][r]);
                        ls += p[r];
                    }
                    pk[st * 2 + 0] = pkbf(p[0], p[1]);
                    pk[st * 2 + 1] = pkbf(p[2], p[3]);
                }
            } else {
#pragma unroll
                for (int st = 0; st < 4; st++) {
                    float p[4];
#pragma unroll
                    for (int r = 0; r < 4; r++) {
                        p[r] = __builtin_exp2f(saC[st][r]);
                        ls += p[r];
                    }
                    pk[st * 2 + 0] = pkbf(p[0], p[1]);
                    pk[st * 2 + 1] = pkbf(p[2], p[3]);
                }
            }
            ls += __shfl_xor(ls, 16);
            ls += __shfl_xor(ls, 32);
            lC += ls;
#pragma unroll
            for (int st = 0; st < 4; st++) {
                uint2 w; w.x = pk[st * 2]; w.y = pk[st * 2 + 1];
                *(uint2*)&Pw[SWZ(l15, st * 16 + quad * 4)] = w;
            }
#pragma unroll
            for (int c = 0; c < 2; c++) {
                bf16x8 vf[4];
#pragma unroll
                for (int nt = 0; nt < 4; nt++)
                    vf[nt] = *(const bf16x8*)&Vb_[SWZ(nt * 16 + l15, c * 32 + quad * 8)];
                bf16x8 pf = *(const bf16x8*)&Pw[SWZ(l15, c * 32 + quad * 8)];
#pragma unroll
                for (int nt = 0; nt < 4; nt++)
                    accC[nt] = __builtin_amdgcn_mfma_f32_16x16x32_bf16(vf[nt], pf, accC[nt], 0, 0, 0);
            }
        }
        // ---- tile A: softmax -> P (same buffer; in-wave LDS order) -> PV ----
        if (aAct) {
            float ls = 0.f;
            if (kb == tA) {
#pragma unroll
                for (int st = 0; st < 4; st++) {
                    float p[4];
#pragma unroll
                    for (int r = 0; r < 4; r++) {
                        bool msk = (st * 16 + quad * 4 + r > qrel);
                        p[r] = msk ? 0.f : __builtin_exp2f(saA[st][r]);
                        ls += p[r];
                    }
                    pk[st * 2 + 0] = pkbf(p[0], p[1]);
                    pk[st * 2 + 1] = pkbf(p[2], p[3]);
                }
            } else {
#pragma unroll
                for (int st = 0; st < 4; st++) {
                    float p[4];
#pragma unroll
                    for (int r = 0; r < 4; r++) {
                        p[r] = __builtin_exp2f(saA[st][r]);
                        ls += p[r];
                    }
                    pk[st * 2 + 0] = pkbf(p[0], p[1]);
                    pk[st * 2 + 1] = pkbf(p[2], p[3]);
                }
            }
            ls += __shfl_xor(ls, 16);
            ls += __shfl_xor(ls, 32);
            lA += ls;
#pragma unroll
            for (int st = 0; st < 4; st++) {
                uint2 w; w.x = pk[st * 2]; w.y = pk[st * 2 + 1];
                *(uint2*)&Pw[SWZ(l15, st * 16 + quad * 4)] = w;
            }
#pragma unroll
            for (int c = 0; c < 2; c++) {
                bf16x8 vf[4];
#pragma unroll
                for (int nt = 0; nt < 4; nt++)
                    vf[nt] = *(const bf16x8*)&Vb_[SWZ(nt * 16 + l15, c * 32 + quad * 8)];
                bf16x8 pf = *(const bf16x8*)&Pw[SWZ(l15, c * 32 + quad * 8)];
#pragma unroll
                for (int nt = 0; nt < 4; nt++)
                    accA[nt] = __builtin_amdgcn_mfma_f32_16x16x32_bf16(vf[nt], pf, accA[nt], 0, 0, 0);
            }
        }

        __syncthreads();   // drains prefetch vmcnt(0); buf^1 ready, buf free
    }

    const int b = bh >> 4, h = bh & 15;
    {
        const int q = tA * 64 + wv * 16 + l15;
        const float inv = 1.0f / lA;
#pragma unroll
        for (int nt = 0; nt < 4; nt++) {
            uint2 st2;
            st2.x = pkbf(accA[nt][0] * inv, accA[nt][1] * inv);
            st2.y = pkbf(accA[nt][2] * inv, accA[nt][3] * inv);
            *(uint2*)&CTX[((size_t)(b * S_LEN + q)) * D_MODEL + h * HDIM + nt * 16 + quad * 4] = st2;
        }
    }
    {
        const int q = tC * 64 + wv * 16 + l15;
        const float inv = 1.0f / lC;
#pragma unroll
        for (int nt = 0; nt < 4; nt++) {
            uint2 st2;
            st2.x = pkbf(accC[nt][0] * inv, accC[nt][1] * inv);
            st2.y = pkbf(accC[nt][2] * inv, accC[nt][3] * inv);
            *(uint2*)&CTX[((size_t)(b * S_LEN + q)) * D_MODEL + h * HDIM + nt * 16 + quad * 4] = st2;
        }
    }
}

// ---------------- output projection: fp32 out = ctx @ Wo^T + bo --------------
__global__ __launch_bounds__(256, 2) void outproj_kernel(
    const __hip_bfloat16* __restrict__ X, const __hip_bfloat16* __restrict__ W,
    const float* __restrict__ bias, float* __restrict__ OUT) {
    __shared__ __hip_bfloat16 As[2 * 8192];
    __shared__ __hip_bfloat16 Bs[2 * 8192];
    f32x4 acc[4][4];
#pragma unroll
    for (int i = 0; i < 4; i++)
#pragma unroll
        for (int j = 0; j < 4; j++) acc[i][j] = (f32x4){0.f, 0.f, 0.f, 0.f};
    const int m0 = blockIdx.x * 128, n0 = blockIdx.y * 128;
    gemm_mainloop(X, W, As, Bs, m0, n0, acc);
    const int tid = threadIdx.x;
    const int wv = tid >> 6, lane = tid & 63, l15 = lane & 15, quad = lane >> 4;
    const int rw = (wv >> 1) * 64, cw = (wv & 1) * 64;
#pragma unroll
    for (int mt = 0; mt < 4; mt++)
#pragma unroll
        for (int r = 0; r < 4; r++) {
            int m = m0 + rw + mt * 16 + quad * 4 + r;
#pragma unroll
            for (int nt = 0; nt < 4; nt++) {
                int n = n0 + cw + nt * 16 + l15;
                OUT[(size_t)m * D_MODEL + n] = acc[mt][nt][r] + bias[n];
            }
        }
}

extern "C" void kernel_launch(void* const* d_in, const int* in_sizes, int n_in,
                              void* d_out, int out_size, void* d_ws, size_t ws_size,
                              hipStream_t stream) {
    const float* x  = (const float*)d_in[0];
    const float* rc = (const float*)d_in[2];
    const float* rs = (const float*)d_in[3];
    const float* Wq = (const float*)d_in[4];
    const float* bq = (const float*)d_in[5];
    const float* Wk = (const float*)d_in[6];
    const float* bk = (const float*)d_in[7];
    const float* Wv = (const float*)d_in[8];
    const float* bv = (const float*)d_in[9];
    const float* Wo = (const float*)d_in[10];
    const float* bo = (const float*)d_in[11];

    char* ws = (char*)d_ws;
    __hip_bfloat16* xbf = (__hip_bfloat16*)(ws);                    // 16 MB
    __hip_bfloat16* wqb = (__hip_bfloat16*)(ws + (16u << 20));      // 2 MB
    __hip_bfloat16* wkb = (__hip_bfloat16*)(ws + (18u << 20));
    __hip_bfloat16* wvb = (__hip_bfloat16*)(ws + (20u << 20));
    __hip_bfloat16* wob = (__hip_bfloat16*)(ws + (22u << 20));
    __hip_bfloat16* Qb  = (__hip_bfloat16*)(ws + (24u << 20));      // 16 MB
    __hip_bfloat16* Kb  = (__hip_bfloat16*)(ws + (40u << 20));
    __hip_bfloat16* Vb  = (__hip_bfloat16*)(ws + (56u << 20));      // V^T layout
    __hip_bfloat16* Cb  = (__hip_bfloat16*)(ws + (72u << 20));      // 16 MB
    float* out = (float*)d_out;

    f2bf4_kernel<<<8192, 256, 0, stream>>>((const float4*)x, (__hip_bfloat162*)xbf, 2097152);
    f2bfw_kernel<<<dim3(1024, 4), 256, 0, stream>>>(
        (const float4*)Wq, (const float4*)Wk, (const float4*)Wv, (const float4*)Wo,
        (__hip_bfloat162*)wqb, (__hip_bfloat162*)wkb, (__hip_bfloat162*)wvb,
        (__hip_bfloat162*)wob);

    qkv_kernel<<<dim3(64, 8, 3), 256, 0, stream>>>(xbf, wqb, wkb, wvb, bq, bk, bv,
                                                   rc, rs, Qb, Kb, Vb);
    attn_kernel<<<dim3(64, 16), 256, 0, stream>>>(Qb, Kb, Vb, Cb);
    outproj_kernel<<<dim3(64, 8), 256, 0, stream>>>(Cb, wob, bo, out);
}